// Round 6
// baseline (509.957 us; speedup 1.0000x reference)
//
#include <hip/hip_runtime.h>

typedef __bf16 bf16_t;
typedef __bf16 bf16x8 __attribute__((ext_vector_type(8)));
typedef __bf16 bf16x4 __attribute__((ext_vector_type(4)));
typedef __bf16 bf16x2 __attribute__((ext_vector_type(2)));
typedef float f32x4 __attribute__((ext_vector_type(4)));

#define NB 8
#define SQ 2048
#define SK 2048
#define DD 512
#define KP2 1024               // packed hi|lo physical K extent
#define KV 1536                // virtual GEMM K: qh*kh + qh*kl + ql*kh

#define BM 128
#define BN 128
#define BK 32
#define LDK 40   // padded LDS row stride (80 B, 16B-aligned rows for b128)
#define NBLK (SK / BN)   // n-blocks per row = softmax partial count

// ------------------------------------------------- pack: Q,K -> [qh|ql] bf16
// One-time hi/lo split (was done 16x redundantly inside the logits GEMM).
// Also emits k^2 row sums (f32, from the original f32 K).
__global__ __launch_bounds__(256) void pack_kernel(
    const float* __restrict__ Q, const float* __restrict__ K,
    bf16_t* __restrict__ QP, bf16_t* __restrict__ KP, float* __restrict__ Ksq) {
  const int row = blockIdx.x * 4 + (threadIdx.x >> 6);  // 0..NB*SQ-1
  const int lane = threadIdx.x & 63;
  const float* q = Q + (size_t)row * DD;
  const float* k = K + (size_t)row * DD;
  bf16_t* qp = QP + (size_t)row * KP2;
  bf16_t* kp = KP + (size_t)row * KP2;
  float ks = 0.f;
#pragma unroll
  for (int j = 0; j < 2; j++) {
    const int c = lane * 4 + j * 256;
    float4 qv = *(const float4*)(q + c);
    float4 kv = *(const float4*)(k + c);
    bf16_t q0 = (bf16_t)qv.x, q1 = (bf16_t)qv.y, q2 = (bf16_t)qv.z, q3 = (bf16_t)qv.w;
    bf16x4 qh = {q0, q1, q2, q3};
    bf16x4 ql = {(bf16_t)(qv.x - (float)q0), (bf16_t)(qv.y - (float)q1),
                 (bf16_t)(qv.z - (float)q2), (bf16_t)(qv.w - (float)q3)};
    bf16_t c0 = (bf16_t)kv.x, c1 = (bf16_t)kv.y, c2 = (bf16_t)kv.z, c3 = (bf16_t)kv.w;
    bf16x4 kh = {c0, c1, c2, c3};
    bf16x4 kl = {(bf16_t)(kv.x - (float)c0), (bf16_t)(kv.y - (float)c1),
                 (bf16_t)(kv.z - (float)c2), (bf16_t)(kv.w - (float)c3)};
    *(bf16x4*)(qp + c) = qh;
    *(bf16x4*)(qp + 512 + c) = ql;
    *(bf16x4*)(kp + c) = kh;
    *(bf16x4*)(kp + 512 + c) = kl;
    ks = fmaf(kv.x, kv.x, ks);
    ks = fmaf(kv.y, kv.y, ks);
    ks = fmaf(kv.z, kv.z, ks);
    ks = fmaf(kv.w, kv.w, ks);
  }
#pragma unroll
  for (int off = 32; off; off >>= 1) ks += __shfl_xor(ks, off);
  if (lane == 0) Ksq[row] = ks;
}

// ------------------------------------------------- logits = (2 q.k - k^2) * log2e/T
// VIRTUAL K=1536 bf16 GEMM over packed [h|l] operands: per 512-segment the
// wave-uniform offset map pairs (qh,kh), (qh,kl), (ql,kh) -> exactly the
// three-term hi/lo product (round-4 math, absmax 0.031). No in-loop
// conversion VALU, no in-loop k^2. BASE-2 domain. Epilogue emits
// per-(row, n-block) base-2 softmax partials (m_i, s_i).
__global__ __launch_bounds__(256, 2) void logits_kernel(
    const bf16_t* __restrict__ QP, const bf16_t* __restrict__ KPp,
    const float* __restrict__ Ksq, const float* __restrict__ tempP,
    float* __restrict__ logits, float* __restrict__ Mpart, float* __restrict__ Spart) {
  __shared__ bf16_t at[BM][LDK], bt[BN][LDK];
  __shared__ float mred[BM][2], sred[BM][2];
  const int b = blockIdx.z;
  const int m0 = blockIdx.y * BM;
  const int n0 = blockIdx.x * BN;
  const int tid = threadIdx.x;
  const int lane = tid & 63;
  const int wave = tid >> 6;
  const int wm = (wave >> 1) * 64;
  const int wn = (wave & 1) * 64;
  const int lrow = lane & 15;
  const int quad = lane >> 4;

  // staging map: thread -> (row = tid>>1, k8 = (tid&1)*8), loads k8 and k8+16
  const int srow = tid >> 1;        // 0..127
  const int k8 = (tid & 1) * 8;

  const bf16_t* qbase = QP + ((size_t)b * SQ + m0 + srow) * KP2 + k8;
  const bf16_t* kbase = KPp + ((size_t)b * SK + n0 + srow) * KP2 + k8;

  f32x4 acc[4][4];
#pragma unroll
  for (int i = 0; i < 4; i++)
#pragma unroll
    for (int j = 0; j < 4; j++) acc[i][j] = (f32x4){0.f, 0.f, 0.f, 0.f};

  // virtual k=0 -> phys (0,0)
  bf16x8 pa0 = *(const bf16x8*)(qbase);
  bf16x8 pa1 = *(const bf16x8*)(qbase + 16);
  bf16x8 pb0 = *(const bf16x8*)(kbase);
  bf16x8 pb1 = *(const bf16x8*)(kbase + 16);

  for (int kv = 0; kv < KV; kv += BK) {
    __syncthreads();  // previous iteration's LDS reads complete
    *(bf16x8*)&at[srow][k8] = pa0;
    *(bf16x8*)&at[srow][k8 + 16] = pa1;
    *(bf16x8*)&bt[srow][k8] = pb0;
    *(bf16x8*)&bt[srow][k8 + 16] = pb1;
    __syncthreads();

    if (kv + BK < KV) {   // prefetch next k-step (hides under MFMA phase)
      const int kn = kv + BK;
      const int ao = (kn < 512) ? kn : kn - 512;     // qh,qh,ql
      const int bo = (kn < 1024) ? kn : kn - 1024;   // kh,kl,kh
      pa0 = *(const bf16x8*)(qbase + ao);
      pa1 = *(const bf16x8*)(qbase + ao + 16);
      pb0 = *(const bf16x8*)(kbase + bo);
      pb1 = *(const bf16x8*)(kbase + bo + 16);
    }

    bf16x8 bfr[4];
#pragma unroll
    for (int ni = 0; ni < 4; ni++)
      bfr[ni] = *(const bf16x8*)&bt[wn + ni * 16 + lrow][quad * 8];
#pragma unroll
    for (int mi = 0; mi < 4; mi++) {
      bf16x8 a = *(const bf16x8*)&at[wm + mi * 16 + lrow][quad * 8];
#pragma unroll
      for (int ni = 0; ni < 4; ni++)
        acc[mi][ni] = __builtin_amdgcn_mfma_f32_16x16x32_bf16(a, bfr[ni], acc[mi][ni], 0, 0, 0);
    }
  }

  // base-2 pre-scale: logits' = (2 q.k - k^2) * log2(e)/T  (q^2 dropped)
  const float invT = 1.4426950408889634f / tempP[0];
  float* Lb = logits + (size_t)b * SQ * SK;
  const float* ksb = Ksq + (size_t)b * SK + n0;
  float ks4[4];
#pragma unroll
  for (int ni = 0; ni < 4; ni++) ks4[ni] = ksb[wn + ni * 16 + lrow];

#pragma unroll
  for (int mi = 0; mi < 4; mi++) {
#pragma unroll
    for (int r = 0; r < 4; r++) {
      const int row = wm + mi * 16 + quad * 4 + r;
      float sv[4];
#pragma unroll
      for (int ni = 0; ni < 4; ni++) {
        sv[ni] = (2.0f * acc[mi][ni][r] - ks4[ni]) * invT;
        Lb[(size_t)(m0 + row) * SK + (n0 + wn + ni * 16 + lrow)] = sv[ni];
      }
      float rm = fmaxf(fmaxf(sv[0], sv[1]), fmaxf(sv[2], sv[3]));
      rm = fmaxf(rm, __shfl_xor(rm, 1));
      rm = fmaxf(rm, __shfl_xor(rm, 2));
      rm = fmaxf(rm, __shfl_xor(rm, 4));
      rm = fmaxf(rm, __shfl_xor(rm, 8));
      float rs = exp2f(sv[0] - rm) + exp2f(sv[1] - rm) +
                 exp2f(sv[2] - rm) + exp2f(sv[3] - rm);
      rs += __shfl_xor(rs, 1);
      rs += __shfl_xor(rs, 2);
      rs += __shfl_xor(rs, 4);
      rs += __shfl_xor(rs, 8);
      if (lrow == 0) {
        mred[row][wave & 1] = rm;
        sred[row][wave & 1] = rs;
      }
    }
  }
  __syncthreads();
  if (tid < BM) {
    const float ma = mred[tid][0], mb = mred[tid][1];
    const float M = fmaxf(ma, mb);
    const float S = sred[tid][0] * exp2f(ma - M) + sred[tid][1] * exp2f(mb - M);
    const size_t o = ((size_t)b * NBLK + blockIdx.x) * SQ + (m0 + tid);
    Mpart[o] = M;
    Spart[o] = S;
  }
}

// ------------------------------------------------- Vt[b][d][k] bf16 = V^T
__global__ __launch_bounds__(256) void vt_kernel(const float* __restrict__ V,
                                                 bf16_t* __restrict__ Vt) {
  const int b = blockIdx.y;
  const int k0 = blockIdx.x * 32;
  const int tid = threadIdx.x;
  const int p = tid & 15;
  const int c = tid >> 4;
  const float* Vb = V + (size_t)b * SK * DD;
  bf16_t* Vtb = Vt + (size_t)b * DD * SK;
  const int k = k0 + 2 * p;
#pragma unroll
  for (int j = 0; j < 8; j++) {
    const int d0 = 4 * c + 64 * j;
    float4 v0 = *(const float4*)(Vb + (size_t)k * DD + d0);
    float4 v1 = *(const float4*)(Vb + (size_t)(k + 1) * DD + d0);
    bf16x2 t0 = {(bf16_t)v0.x, (bf16_t)v1.x};
    bf16x2 t1 = {(bf16_t)v0.y, (bf16_t)v1.y};
    bf16x2 t2 = {(bf16_t)v0.z, (bf16_t)v1.z};
    bf16x2 t3 = {(bf16_t)v0.w, (bf16_t)v1.w};
    *(bf16x2*)(Vtb + (size_t)(d0 + 0) * SK + k) = t0;
    *(bf16x2*)(Vtb + (size_t)(d0 + 1) * SK + k) = t1;
    *(bf16x2*)(Vtb + (size_t)(d0 + 2) * SK + k) = t2;
    *(bf16x2*)(Vtb + (size_t)(d0 + 3) * SK + k) = t3;
  }
}

// ------------------------------------------------- fused softmax + O = W @ V
// Chunked double-buffered panel, DEPTH-2 register prefetch (load chunk c+2
// while computing chunk c). bw0/bw1 statically indexed (no scratch).
#define PM 32
#define CK 256                 // k-chunk elements
#define CKB 512                // chunk row bytes
#define NCH (SK / CK)          // 8 chunks
#define NWIN (SK / BK)         // 64 k-windows

__device__ __forceinline__ unsigned pv_lds(int row, unsigned kb) {
  return (unsigned)row * CKB + (kb ^ (unsigned)((row & 7) << 4));
}

__global__ __launch_bounds__(512, 4) void pv_kernel(
    float* __restrict__ L,               // raw logits in, weights out (in place)
    const bf16_t* __restrict__ Vt,
    const float* __restrict__ Mpart, const float* __restrict__ Spart,
    float* __restrict__ O) {
  __shared__ __align__(16) unsigned char wlds[2][PM * CKB];  // 2 x 16 KB
  __shared__ float Msh[PM], Ssh[PM];
  const int bid = blockIdx.x;
  const int b = bid & 7;            // XCD affinity: batch b -> XCD b
  const int m0 = (bid >> 3) * PM;
  const int tid = threadIdx.x;

  float* Lb = L + (size_t)b * SQ * SK;
  const bf16_t* Vtb = Vt + (size_t)b * DD * SK;

  // ---- combine base-2 split-softmax partials: 16 threads/row, 1 partial ea.
  {
    const int row = tid >> 4;       // 0..31
    const int j = tid & 15;
    const size_t o = ((size_t)b * NBLK + j) * SQ + (m0 + row);
    const float pm = Mpart[o];
    const float ps = Spart[o];
    float m = pm;
    m = fmaxf(m, __shfl_xor(m, 1));
    m = fmaxf(m, __shfl_xor(m, 2));
    m = fmaxf(m, __shfl_xor(m, 4));
    m = fmaxf(m, __shfl_xor(m, 8));
    float s = ps * exp2f(pm - m);
    s += __shfl_xor(s, 1);
    s += __shfl_xor(s, 2);
    s += __shfl_xor(s, 4);
    s += __shfl_xor(s, 8);
    if (j == 0) {
      Msh[row] = m;
      Ssh[row] = 1.0f / s;
    }
  }
  __syncthreads();

  // ---- staging identity: thread (prow, g) owns k = g*4 + j*64, j=0..3
  const int prow = tid >> 4;        // 0..31
  const int g = tid & 15;
  float* lp = Lb + (size_t)(m0 + prow) * SK;
  const float Mrow = Msh[prow];
  const float invS = Ssh[prow];

  auto stage = [&](const float4 (&pv4)[4], int c1) {
    unsigned char* buf = wlds[c1 & 1];
    const int kbase = c1 * CK;
#pragma unroll
    for (int j = 0; j < 4; j++) {
      const int k = g * 4 + j * 64;
      float4 v = pv4[j];
      const float w0 = exp2f(v.x - Mrow) * invS;
      const float w1 = exp2f(v.y - Mrow) * invS;
      const float w2 = exp2f(v.z - Mrow) * invS;
      const float w3 = exp2f(v.w - Mrow) * invS;
      *(float4*)(lp + kbase + k) = make_float4(w0, w1, w2, w3);  // W output
      bf16x4 w4 = {(bf16_t)w0, (bf16_t)w1, (bf16_t)w2, (bf16_t)w3};
      *(bf16x4*)(buf + pv_lds(prow, (unsigned)(k * 2))) = w4;
    }
  };

  // ---- GEMM identity
  const int lane = tid & 63;
  const int wave = tid >> 6;        // 0..7
  const int wn = wave * 64;
  const int lrow = lane & 15;
  const int quad = lane >> 4;

  const bf16_t* Brow[4];
#pragma unroll
  for (int ni = 0; ni < 4; ni++)
    Brow[ni] = Vtb + (size_t)(wn + ni * 16 + lrow) * SK + quad * 8;

  f32x4 acc[2][4];
#pragma unroll
  for (int i = 0; i < 2; i++)
#pragma unroll
    for (int j = 0; j < 4; j++) acc[i][j] = (f32x4){0.f, 0.f, 0.f, 0.f};

  // ---- prologue: stage chunk 0; pA <- chunk 1; B windows 0,1
  {
    float4 p0[4];
#pragma unroll
    for (int j = 0; j < 4; j++) p0[j] = *(const float4*)(lp + g * 4 + j * 64);
    stage(p0, 0);
  }
  float4 pA[4];
#pragma unroll
  for (int j = 0; j < 4; j++) pA[j] = *(const float4*)(lp + CK + g * 4 + j * 64);

  bf16x8 bw0[4], bw1[4];
#pragma unroll
  for (int ni = 0; ni < 4; ni++) bw0[ni] = *(const bf16x8*)(Brow[ni]);
#pragma unroll
  for (int ni = 0; ni < 4; ni++) bw1[ni] = *(const bf16x8*)(Brow[ni] + BK);
  __syncthreads();

  for (int c = 0; c < NCH; c++) {
    // issue chunk c+2 raw-L loads (two chunks of compute to cover latency)
    float4 pB_[4] = {};
    if (c + 2 < NCH) {
      const int kbase = (c + 2) * CK;
#pragma unroll
      for (int j = 0; j < 4; j++)
        pB_[j] = *(const float4*)(lp + kbase + g * 4 + j * 64);
    }

    // GEMM this chunk's 8 windows; static bw0/bw1 parity; prefetch 2 ahead
    const unsigned char* buf = wlds[c & 1];
#pragma unroll
    for (int w = 0; w < CK / BK; w += 2) {
      const int gw = c * (CK / BK) + w;
      {
        bf16x8 a0 = *(const bf16x8*)(buf + pv_lds(lrow, (unsigned)(w * 64 + quad * 16)));
        bf16x8 a1 = *(const bf16x8*)(buf + pv_lds(16 + lrow, (unsigned)(w * 64 + quad * 16)));
#pragma unroll
        for (int ni = 0; ni < 4; ni++)
          acc[0][ni] = __builtin_amdgcn_mfma_f32_16x16x32_bf16(a0, bw0[ni], acc[0][ni], 0, 0, 0);
#pragma unroll
        for (int ni = 0; ni < 4; ni++)
          acc[1][ni] = __builtin_amdgcn_mfma_f32_16x16x32_bf16(a1, bw0[ni], acc[1][ni], 0, 0, 0);
        if (gw + 2 < NWIN) {
#pragma unroll
          for (int ni = 0; ni < 4; ni++)
            bw0[ni] = *(const bf16x8*)(Brow[ni] + (gw + 2) * BK);
        }
      }
      {
        bf16x8 a0 = *(const bf16x8*)(buf + pv_lds(lrow, (unsigned)((w + 1) * 64 + quad * 16)));
        bf16x8 a1 = *(const bf16x8*)(buf + pv_lds(16 + lrow, (unsigned)((w + 1) * 64 + quad * 16)));
#pragma unroll
        for (int ni = 0; ni < 4; ni++)
          acc[0][ni] = __builtin_amdgcn_mfma_f32_16x16x32_bf16(a0, bw1[ni], acc[0][ni], 0, 0, 0);
#pragma unroll
        for (int ni = 0; ni < 4; ni++)
          acc[1][ni] = __builtin_amdgcn_mfma_f32_16x16x32_bf16(a1, bw1[ni], acc[1][ni], 0, 0, 0);
        if (gw + 3 < NWIN) {
#pragma unroll
          for (int ni = 0; ni < 4; ni++)
            bw1[ni] = *(const bf16x8*)(Brow[ni] + (gw + 3) * BK);
        }
      }
    }

    if (c + 1 < NCH) {
      stage(pA, c + 1);  // uses loads issued LAST iteration (fully covered)
      // LDS-visibility-only barrier: global prefetches stay in flight
      asm volatile("s_waitcnt lgkmcnt(0)\n\ts_barrier" ::: "memory");
    }
#pragma unroll
    for (int j = 0; j < 4; j++) pA[j] = pB_[j];
  }

  float* Ob = O + (size_t)b * SQ * DD;
#pragma unroll
  for (int ni = 0; ni < 4; ni++) {
    const int d = wn + ni * 16 + lrow;
#pragma unroll
    for (int mi = 0; mi < 2; mi++) {
      const int mbase = m0 + mi * 16 + quad * 4;
#pragma unroll
      for (int r = 0; r < 4; r++) {
        Ob[(size_t)(mbase + r) * DD + d] = acc[mi][ni][r];
      }
    }
  }
}

extern "C" void kernel_launch(void* const* d_in, const int* in_sizes, int n_in,
                              void* d_out, int out_size, void* d_ws, size_t ws_size,
                              hipStream_t stream) {
  const float* Q = (const float*)d_in[0];
  const float* K = (const float*)d_in[1];
  const float* V = (const float*)d_in[2];
  const float* T = (const float*)d_in[3];

  float* outv = (float*)d_out;                          // [8,2048,512]
  float* logits = outv + (size_t)NB * SQ * DD;          // [8,2048,2048] weights region

  // workspace layout (~86 MB): partials 2 MB | Vt 16.8 MB | QP 33.6 | KP 33.6 | Ksq 64 KB
  float* Mpart = (float*)d_ws;
  float* Spart = Mpart + (size_t)NB * NBLK * SQ;
  bf16_t* Vt = (bf16_t*)(Spart + (size_t)NB * NBLK * SQ);
  bf16_t* QP = Vt + (size_t)NB * DD * SK;
  bf16_t* KPp = QP + (size_t)NB * SQ * KP2;
  float* Ksq = (float*)(KPp + (size_t)NB * SK * KP2);

  pack_kernel<<<NB * SQ / 4, 256, 0, stream>>>(Q, K, QP, KPp, Ksq);
  vt_kernel<<<dim3(SK / 32, NB), 256, 0, stream>>>(V, Vt);
  logits_kernel<<<dim3(SK / BN, SQ / BM, NB), 256, 0, stream>>>(QP, KPp, Ksq, T,
                                                                logits, Mpart, Spart);
  pv_kernel<<<dim3(NB * (SQ / PM)), 512, 0, stream>>>(logits, Vt, Mpart, Spart, outv);
}